// Round 13
// baseline (149.365 us; speedup 1.0000x reference)
//
#include <hip/hip_runtime.h>
#include <hip/hip_bf16.h>

// Problem constants (B=1)
constexpr int kS   = 2048;
constexpr int kD   = 2048;
constexpr int kG   = 8;
constexpr int kHD  = 64;
constexpr int kGHD = 512;
constexpr int kNQKV = kD + 2 * kGHD;   // 3072 fused QKV output cols

// 0.125 (1/sqrt(HD)) * log2(e): folds softmax scale AND exp->exp2 into Wq/bq
constexpr float kQScale = 0.125f * 1.4426950408889634f;

typedef __attribute__((ext_vector_type(8)))  _Float16 f16x8;
typedef __attribute__((ext_vector_type(4)))  float    f32x4;
typedef __attribute__((ext_vector_type(16))) float    f32x16;
typedef __attribute__((ext_vector_type(4)))  unsigned int u32x4;

__device__ __forceinline__ ushort f2h(float x) {
    return __builtin_bit_cast(ushort, (_Float16)x);
}
__device__ __forceinline__ float fast_exp2(float x) {
    return __builtin_amdgcn_exp2f(x);   // v_exp_f32 is base-2
}
__device__ __forceinline__ unsigned int pkrtz(float a, float b) {
    auto r = __builtin_amdgcn_cvt_pkrtz(a, b);   // lo = a, hi = b
    return __builtin_bit_cast(unsigned int, r);
}

// ---------------------------------------------------------------------------
// ONE fused conversion kernel: x,Wq,Wk,Wv,Wo -> f16 (+scale on Wq), bias vec.
// ---------------------------------------------------------------------------
__global__ __launch_bounds__(256) void cvt_all(
    const float* __restrict__ x,  const float* __restrict__ Wq,
    const float* __restrict__ Wk, const float* __restrict__ Wv,
    const float* __restrict__ Wo, const float* __restrict__ bq,
    const float* __restrict__ bk, const float* __restrict__ bv,
    ushort* __restrict__ xf, ushort* __restrict__ wqkvf,
    ushort* __restrict__ wof, float* __restrict__ bqkv)
{
    constexpr size_t Nx  = (size_t)kS * kD;
    constexpr size_t NWq = (size_t)kD * kD;
    constexpr size_t NWk = (size_t)kGHD * kD;
    constexpr size_t e1 = Nx, e2 = e1 + NWq, e3 = e2 + NWk, e4 = e3 + NWk,
                     e5 = e4 + NWq;
    const size_t i = ((size_t)blockIdx.x * 256 + threadIdx.x) * 4;

    const float* src; ushort* dst; float scale = 1.f;
    if (i < e1)      { src = x  + i;        dst = xf + i; }
    else if (i < e2) { src = Wq + (i - e1); dst = wqkvf + (i - e1); scale = kQScale; }
    else if (i < e3) { src = Wk + (i - e2); dst = wqkvf + NWq + (i - e2); }
    else if (i < e4) { src = Wv + (i - e3); dst = wqkvf + NWq + NWk + (i - e3); }
    else if (i < e5) { src = Wo + (i - e4); dst = wof + (i - e4); }
    else {
        const size_t j = i - e5;   // bias segment [0, 3072)
        #pragma unroll
        for (int u = 0; u < 4; ++u) {
            const size_t jj = j + u;
            if (jj < kD)              bqkv[jj] = bq[jj] * kQScale;
            else if (jj < kD + kGHD)  bqkv[jj] = bk[jj - kD];
            else if (jj < (size_t)kNQKV) bqkv[jj] = bv[jj - kD - kGHD];
        }
        return;
    }
    const float4 v = *(const float4*)src;
    ushort4 o;
    o.x = f2h(v.x * scale); o.y = f2h(v.y * scale);
    o.z = f2h(v.z * scale); o.w = f2h(v.w * scale);
    *(ushort4*)dst = o;
}

// ---------------------------------------------------------------------------
// XCD-bijective block swizzle (grids here are multiples of 8)
// ---------------------------------------------------------------------------
__device__ __forceinline__ int xcd_swizzle(int orig, int nwg) {
    const int cpx = nwg >> 3;
    return (orig & 7) * cpx + (orig >> 3);
}

// ---------------------------------------------------------------------------
// 16-wave 128x128 f16 GEMM, 4-way K-PHASE SPLIT (R13):
//   1024 threads = 16 waves; kph = w>>2 quarters the K-loop (BK=128 staged,
//   wave kph computes k in [kph*32, kph*32+32) of each 128-k step);
//   sub = w&3 -> 2x2 wave-grid of square 64x64 output tiles (2.0 MFMA/read).
//   Staging: waves 0-7 stage A rows, 8-15 stage B rows (4 issues x 4 rows).
//   16 waves/CU = 4/SIMD (vs 2 for the R12 gemm_o); barriers halve (16 steps).
//   4 K-phase partials merged in 2 steps through the dead 128 KB staging LDS.
// XOR swizzle both-sides: linear LDS dest, pre-swizzled global source slot
// (slot ^ (row&7)), swizzled read slot ((kph*4+kq) ^ (row&7)).
// ---------------------------------------------------------------------------
#define GEMM_PRELUDE(Aptr, Bptr)                                              \
    const int bid  = xcd_swizzle(blockIdx.x, gridDim.x);                      \
    const int m0   = (bid / gridX) * 128;                                     \
    const int n0   = (bid % gridX) * 128;                                     \
    const int tid  = threadIdx.x;                                             \
    const int w    = tid >> 6;            /* 0..15 */                         \
    const int lane = tid & 63;                                                \
    const int kph  = w >> 2;              /* K-phase 0..3 */                  \
    const int sub  = w & 3;               /* wave-grid pos */                 \
    const int wm   = sub >> 1;                                                \
    const int wn   = sub & 1;                                                 \
    const int fr   = lane & 15;                                               \
    const int kq   = lane >> 4;           /* 0..3 */                          \
    const int smat   = w >> 3;            /* 0: stage A, 1: stage B */        \
    const int srbase = (w & 7) * 16;      /* 16 rows per wave */              \
    const int srsub  = lane >> 4;         /* row within 4-row issue */        \
    const int sslot  = lane & 15;         /* dest 16B slot (128-k row) */     \
    const ushort* gS = smat ? (Bptr) + (size_t)(n0 + srbase) * K              \
                            : (Aptr) + (size_t)(m0 + srbase) * K;             \
    f32x4 acc[4][4];                                                          \
    _Pragma("unroll")                                                         \
    for (int mi = 0; mi < 4; ++mi)                                            \
        _Pragma("unroll")                                                     \
        for (int ni = 0; ni < 4; ++ni) {                                      \
            f32x4 z = {0.f, 0.f, 0.f, 0.f};                                   \
            acc[mi][ni] = z;                                                  \
        }

#define GEMM_STAGE(buf, k0)                                                   \
    do {                                                                      \
        _Pragma("unroll")                                                     \
        for (int j = 0; j < 4; ++j) {                                         \
            const int rr = j * 4 + srsub;          /* row offset in wave */   \
            const int s  = sslot ^ (rr & 7);       /* pre-swizzled source */  \
            __builtin_amdgcn_global_load_lds(                                 \
                (const __attribute__((address_space(1))) void*)               \
                    (gS + (size_t)rr * K + (k0) + s * 8),                     \
                (__attribute__((address_space(3))) void*)                    \
                    &lds[buf][smat][(srbase + j * 4) * 128],                  \
                16, 0, 0);                                                    \
        }                                                                     \
    } while (0)

#define GEMM_KLOOP                                                            \
    GEMM_STAGE(0, 0);                                                         \
    __syncthreads();                                                          \
    int cur = 0;                                                              \
    for (int k0 = 0; k0 < K; k0 += 128) {                                     \
        if (k0 + 128 < K) GEMM_STAGE(cur ^ 1, k0 + 128);                      \
        f16x8 af[4], bf[4];                                                   \
        _Pragma("unroll")                                                     \
        for (int f = 0; f < 4; ++f) {                                         \
            const int ra = wm * 64 + f * 16 + fr;                             \
            const int rb = wn * 64 + f * 16 + fr;                             \
            af[f] = *(const f16x8*)&lds[cur][0][ra * 128                      \
                        + (((kph * 4 + kq) ^ (ra & 7)) * 8)];                 \
            bf[f] = *(const f16x8*)&lds[cur][1][rb * 128                      \
                        + (((kph * 4 + kq) ^ (rb & 7)) * 8)];                 \
        }                                                                     \
        __builtin_amdgcn_s_setprio(1);                                        \
        _Pragma("unroll")                                                     \
        for (int mi = 0; mi < 4; ++mi)                                        \
            _Pragma("unroll")                                                 \
            for (int ni = 0; ni < 4; ++ni)                                    \
                acc[mi][ni] = __builtin_amdgcn_mfma_f32_16x16x32_f16(         \
                    af[mi], bf[ni], acc[mi][ni], 0, 0, 0);                    \
        __builtin_amdgcn_s_setprio(0);                                        \
        __syncthreads();                                                      \
        cur ^= 1;                                                             \
    }

// two-step merge of 4 K-phase partials through the dead staging LDS
// (8 waves x 64 lanes x 64 f32 = 128 KB = exactly the staging size)
#define GEMM_MERGE                                                            \
    float* mlds = (float*)&lds[0][0][0];                                      \
    if (kph & 1) {                                                            \
        const int d = (kph >> 1) * 4 + sub;                                   \
        _Pragma("unroll")                                                     \
        for (int c = 0; c < 16; ++c)                                          \
            *(f32x4*)&mlds[d * 4096 + c * 256 + lane * 4] = acc[c >> 2][c & 3]; \
    }                                                                         \
    __syncthreads();                                                          \
    if (!(kph & 1)) {                                                         \
        const int d = (kph >> 1) * 4 + sub;                                   \
        _Pragma("unroll")                                                     \
        for (int c = 0; c < 16; ++c) {                                        \
            const f32x4 part = *(const f32x4*)&mlds[d * 4096 + c * 256 + lane * 4]; \
            acc[c >> 2][c & 3] += part;                                       \
        }                                                                     \
    }                                                                         \
    __syncthreads();                                                          \
    if (kph == 2) {                                                           \
        _Pragma("unroll")                                                     \
        for (int c = 0; c < 16; ++c)                                          \
            *(f32x4*)&mlds[sub * 4096 + c * 256 + lane * 4] = acc[c >> 2][c & 3]; \
    }                                                                         \
    __syncthreads();                                                          \
    if (kph == 0) {                                                           \
        _Pragma("unroll")                                                     \
        for (int c = 0; c < 16; ++c) {                                        \
            const f32x4 part = *(const f32x4*)&mlds[sub * 4096 + c * 256 + lane * 4]; \
            acc[c >> 2][c & 3] += part;                                       \
        }                                                                     \
    }

// ---------------------------------------------------------------------------
// QKV GEMM: C = A @ B^T + bias -> f16; q [S][D], k [S][GHD], v^T [GHD][S]
// ---------------------------------------------------------------------------
__global__ __launch_bounds__(1024, 4) void gemm_qkv(
    const ushort* __restrict__ Af, const ushort* __restrict__ Bf,
    const float* __restrict__ bias,
    ushort* __restrict__ qb16, ushort* __restrict__ kb16, ushort* __restrict__ vt16,
    int K, int gridX)
{
    __shared__ ushort lds[2][2][128 * 128];   // [buf][A/B], 128 KB

    GEMM_PRELUDE(Af, Bf)
    GEMM_KLOOP
    GEMM_MERGE

    if (kph == 0) {
        const int seg = (n0 < kD) ? 0 : (n0 < kD + kGHD) ? 1 : 2;
        #pragma unroll
        for (int ni = 0; ni < 4; ++ni) {
            const int ncol = n0 + wn * 64 + ni * 16 + fr;
            const float bv = bias[ncol];
            #pragma unroll
            for (int mi = 0; mi < 4; ++mi) {
                #pragma unroll
                for (int i = 0; i < 4; ++i) {
                    const int row = m0 + wm * 64 + mi * 16 + kq * 4 + i;
                    const ushort u = f2h(acc[mi][ni][i] + bv);
                    if (seg == 0)      qb16[(size_t)row * kD   + ncol]              = u;
                    else if (seg == 1) kb16[(size_t)row * kGHD + (ncol - kD)]       = u;
                    else               vt16[(size_t)(ncol - kD - kGHD) * kS + row]  = u;
                }
            }
        }
    }
}

// ---------------------------------------------------------------------------
// O-proj GEMM: out(fp32) = A @ W^T + bias  (single-f16 A)
// ---------------------------------------------------------------------------
__global__ __launch_bounds__(1024, 4) void gemm_o(
    const ushort* __restrict__ Af, const ushort* __restrict__ Bf,
    const float* __restrict__ bias, float* __restrict__ C, int K, int N, int gridX)
{
    __shared__ ushort lds[2][2][128 * 128];

    GEMM_PRELUDE(Af, Bf)
    GEMM_KLOOP
    GEMM_MERGE

    if (kph == 0) {
        #pragma unroll
        for (int ni = 0; ni < 4; ++ni) {
            const int ncol = n0 + wn * 64 + ni * 16 + fr;
            const float bv = bias[ncol];
            #pragma unroll
            for (int mi = 0; mi < 4; ++mi)
                #pragma unroll
                for (int i = 0; i < 4; ++i) {
                    const int row = m0 + wm * 64 + mi * 16 + kq * 4 + i;
                    C[(size_t)row * N + ncol] = acc[mi][ni][i] + bv;
                }
        }
    }
}

// ---------------------------------------------------------------------------
// MFMA flash attention (FROZEN from R11: 32x32x16 f16, in-register P via
// cvt_pkrtz + permlane32_swap, in-block kv-split, flash-decode merge).
// ---------------------------------------------------------------------------
__global__ __launch_bounds__(512, 4) void gqa_attn_mfma(
    const ushort* __restrict__ qb,   // [S][D] f16 (prescaled by kQScale)
    const ushort* __restrict__ kb,   // [S][GHD] f16
    const ushort* __restrict__ vt,   // [GHD][S] f16 (V transposed)
    ushort* __restrict__ oh)
{
    __shared__ ushort Kt[2][2][64 * 64];   // [half][dbuf] swizzled K (32 KB)
    __shared__ ushort Vt[2][2][64 * 64];   // [half][dbuf] swizzled V^T (32 KB)

    const int g    = blockIdx.y;
    const int q0   = blockIdx.x * 32;
    const int tid  = threadIdx.x;
    const int w    = tid >> 6;
    const int lane = tid & 63;
    const int hw   = w & 3;             // head-in-group
    const int half = w >> 2;            // kv half
    const int ql   = lane & 31;         // q-col for this lane
    const int hi   = lane >> 5;
    const int h    = g * 4 + hw;
    const int tbase = half * (kS / 2);

    const int r0 = hw * 16 + (lane >> 3);
    const int ss = (lane & 7) ^ (r0 & 7);   // pre-swizzled source slot

#define ATTN_STAGE(buf, t)                                                         \
    do {                                                                           \
        __builtin_amdgcn_global_load_lds(                                          \
            (const __attribute__((address_space(1))) void*)                       \
                (kb + (size_t)(tbase + (t) + r0) * kGHD + g * kHD + ss * 8),       \
            (__attribute__((address_space(3))) void*)(&Kt[half][buf][(hw * 16) * 64]), \
            16, 0, 0);                                                             \
        __builtin_amdgcn_global_load_lds(                                          \
            (const __attribute__((address_space(1))) void*)                       \
                (kb + (size_t)(tbase + (t) + r0 + 8) * kGHD + g * kHD + ss * 8),   \
            (__attribute__((address_space(3))) void*)(&Kt[half][buf][(hw * 16 + 8) * 64]), \
            16, 0, 0);                                                             \
        __builtin_amdgcn_global_load_lds(                                          \
            (const __attribute__((address_space(1))) void*)                       \
                (vt + (size_t)(g * kHD + r0) * kS + tbase + (t) + ss * 8),         \
            (__attribute__((address_space(3))) void*)(&Vt[half][buf][(hw * 16) * 64]), \
            16, 0, 0);                                                             \
        __builtin_amdgcn_global_load_lds(                                          \
            (const __attribute__((address_space(1))) void*)                       \
                (vt + (size_t)(g * kHD + r0 + 8) * kS + tbase + (t) + ss * 8),     \
            (__attribute__((address_space(3))) void*)(&Vt[half][buf][(hw * 16 + 8) * 64]), \
            16, 0, 0);                                                             \
    } while (0)

    ATTN_STAGE(0, 0);

    // hoist Q fragments (B-operand: lane&31 = q-col, hi = d-half-of-16)
    f16x8 qf[4];
    #pragma unroll
    for (int ks = 0; ks < 4; ++ks)
        qf[ks] = *(const f16x8*)&qb[(size_t)(q0 + ql) * kD + h * kHD + ks * 16 + hi * 8];

    float mrow = -1e30f, lrow = 0.f;    // stats for q = q0 + ql (lane-local)
    f32x16 oacc[2];
    #pragma unroll
    for (int db = 0; db < 2; ++db)
        #pragma unroll
        for (int r = 0; r < 16; ++r) oacc[db][r] = 0.f;

    int cur = 0;
    for (int t = 0; t < kS / 2; t += 64) {
        __syncthreads();   // buf[cur] staged (vmcnt drained); buf[cur^1] reads done

        if (t + 64 < kS / 2) ATTN_STAGE(cur ^ 1, t + 64);

        // --- QK^T (swapped): all 8 K-frag reads, then one MFMA cluster ---
        f32x16 sc[2];
        #pragma unroll
        for (int kb2 = 0; kb2 < 2; ++kb2)
            #pragma unroll
            for (int r = 0; r < 16; ++r) sc[kb2][r] = 0.f;

        {
            f16x8 kf[2][4];
            #pragma unroll
            for (int kb2 = 0; kb2 < 2; ++kb2)
                #pragma unroll
                for (int ks = 0; ks < 4; ++ks)
                    kf[kb2][ks] = *(const f16x8*)&Kt[half][cur][(kb2 * 32 + ql) * 64
                                       + (((2 * ks + hi) ^ (ql & 7)) * 8)];
            __builtin_amdgcn_s_setprio(1);
            #pragma unroll
            for (int ks = 0; ks < 4; ++ks) {
                sc[0] = __builtin_amdgcn_mfma_f32_32x32x16_f16(kf[0][ks], qf[ks], sc[0], 0, 0, 0);
                sc[1] = __builtin_amdgcn_mfma_f32_32x32x16_f16(kf[1][ks], qf[ks], sc[1], 0, 0, 0);
            }
            __builtin_amdgcn_s_setprio(0);
        }

        // --- in-lane softmax: 32 values per lane, 1 shfl per reduce ---
        float mt = sc[0][0];
        #pragma unroll
        for (int kb2 = 0; kb2 < 2; ++kb2)
            #pragma unroll
            for (int r = 0; r < 16; ++r) mt = fmaxf(mt, sc[kb2][r]);
        mt = fmaxf(mt, __shfl_xor(mt, 32));

        if (__any(mt > mrow + 11.5f)) {      // defer-max (T13), log2 domain
            const float mnew = (mt > mrow + 11.5f) ? mt : mrow;
            const float c = fast_exp2(mrow - mnew);
            lrow *= c;
            mrow = mnew;
            #pragma unroll
            for (int db = 0; db < 2; ++db)
                #pragma unroll
                for (int r = 0; r < 16; ++r) oacc[db][r] *= c;
        }

        float ps = 0.f;
        #pragma unroll
        for (int kb2 = 0; kb2 < 2; ++kb2)
            #pragma unroll
            for (int r = 0; r < 16; ++r) {
                const float p = fast_exp2(sc[kb2][r] - mrow);
                sc[kb2][r] = p;
                ps += p;
            }
        ps += __shfl_xor(ps, 32);
        lrow += ps;

        // --- PV: build P-frags, all 8 V-frag reads, one MFMA cluster ---
        {
            f16x8 pf[2][2];
            #pragma unroll
            for (int kb2 = 0; kb2 < 2; ++kb2)
                #pragma unroll
                for (int ks = 0; ks < 2; ++ks) {
                    unsigned int a0 = pkrtz(sc[kb2][8 * ks + 0], sc[kb2][8 * ks + 1]);
                    unsigned int a1 = pkrtz(sc[kb2][8 * ks + 2], sc[kb2][8 * ks + 3]);
                    unsigned int b0 = pkrtz(sc[kb2][8 * ks + 4], sc[kb2][8 * ks + 5]);
                    unsigned int b1 = pkrtz(sc[kb2][8 * ks + 6], sc[kb2][8 * ks + 7]);
                    asm volatile("v_permlane32_swap_b32 %0, %1" : "+v"(a0), "+v"(b0));
                    asm volatile("v_permlane32_swap_b32 %0, %1" : "+v"(a1), "+v"(b1));
                    const u32x4 pu = {a0, a1, b0, b1};
                    pf[kb2][ks] = __builtin_bit_cast(f16x8, pu);
                }
            f16x8 vf[2][2][2];
            #pragma unroll
            for (int kb2 = 0; kb2 < 2; ++kb2)
                #pragma unroll
                for (int ks = 0; ks < 2; ++ks)
                    #pragma unroll
                    for (int db = 0; db < 2; ++db)
                        vf[kb2][ks][db] = *(const f16x8*)&Vt[half][cur][(db * 32 + ql) * 64
                                             + (((4 * kb2 + 2 * ks + hi) ^ (ql & 7)) * 8)];
            __builtin_amdgcn_s_setprio(1);
            #pragma unroll
            for (int kb2 = 0; kb2 < 2; ++kb2)
                #pragma unroll
                for (int ks = 0; ks < 2; ++ks)
                    #pragma unroll
                    for (int db = 0; db < 2; ++db)
                        oacc[db] = __builtin_amdgcn_mfma_f32_32x32x16_f16(
                            vf[kb2][ks][db], pf[kb2][ks], oacc[db], 0, 0, 0);
            __builtin_amdgcn_s_setprio(0);
        }
        cur ^= 1;
    }
#undef ATTN_STAGE

    // --- flash-decode merge of the two kv-halves via (dead) staging LDS ---
    __syncthreads();   // all waves done with K/V tiles
    float* ox  = (float*)(&Kt[0][0][0]);   // [32 regs][256 (head,lane)] = 32 KB
    float* mlx = (float*)(&Vt[0][0][0]);   // [2][256]
    const int idx = hw * 64 + lane;

    if (half == 1) {
        #pragma unroll
        for (int db = 0; db < 2; ++db)
            #pragma unroll
            for (int r = 0; r < 16; ++r)
                ox[(db * 16 + r) * 256 + idx] = oacc[db][r];
        mlx[idx]       = mrow;
        mlx[256 + idx] = lrow;
    }
    __syncthreads();

    if (half == 0) {
        const float m2 = mlx[idx];
        const float l2 = mlx[256 + idx];
        const float mm = fmaxf(mrow, m2);
        const float c1 = fast_exp2(mrow - mm);
        const float c2 = fast_exp2(m2 - mm);
        const float inv = 1.f / (lrow * c1 + l2 * c2);
        const size_t rowbase = (size_t)(q0 + ql) * kD + hw * kGHD + g * kHD;
        #pragma unroll
        for (int db = 0; db < 2; ++db) {
            #pragma unroll
            for (int rr = 0; rr < 4; ++rr) {
                ushort4 o4;
                o4.x = f2h((oacc[db][rr * 4 + 0] * c1 + ox[(db * 16 + rr * 4 + 0) * 256 + idx] * c2) * inv);
                o4.y = f2h((oacc[db][rr * 4 + 1] * c1 + ox[(db * 16 + rr * 4 + 1) * 256 + idx] * c2) * inv);
                o4.z = f2h((oacc[db][rr * 4 + 2] * c1 + ox[(db * 16 + rr * 4 + 2) * 256 + idx] * c2) * inv);
                o4.w = f2h((oacc[db][rr * 4 + 3] * c1 + ox[(db * 16 + rr * 4 + 3) * 256 + idx] * c2) * inv);
                *(ushort4*)&oh[rowbase + db * 32 + rr * 8 + hi * 4] = o4;
            }
        }
    }
}

// ---------------------------------------------------------------------------
extern "C" void kernel_launch(void* const* d_in, const int* in_sizes, int n_in,
                              void* d_out, int out_size, void* d_ws, size_t ws_size,
                              hipStream_t stream)
{
    const float* x  = (const float*)d_in[0];
    const float* Wq = (const float*)d_in[1];
    const float* bq = (const float*)d_in[2];
    const float* Wk = (const float*)d_in[3];
    const float* bk = (const float*)d_in[4];
    const float* Wv = (const float*)d_in[5];
    const float* bv = (const float*)d_in[6];
    const float* Wo = (const float*)d_in[7];
    const float* bo = (const float*)d_in[8];
    float* out = (float*)d_out;

    // workspace layout (~48 MB)
    char* p = (char*)d_ws;
    ushort* xf    = (ushort*)p; p += (size_t)kS * kD * 2;        // x f16
    ushort* wqkvf = (ushort*)p; p += (size_t)kNQKV * kD * 2;     // Wqkv f16 (Wq pre-scaled)
    ushort* wof   = (ushort*)p; p += (size_t)kD * kD * 2;        // Wo f16
    float*  bqkv  = (float*)p;  p += 16384;
    ushort* qb16  = (ushort*)p; p += (size_t)kS * kD * 2;
    ushort* kb16  = (ushort*)p; p += (size_t)kS * kGHD * 2;
    ushort* vt16  = (ushort*)p; p += (size_t)kGHD * kS * 2;
    ushort* aoh   = (ushort*)p;                                  // attn out f16

    // single fused conversion pass (x, Wq*s, Wk, Wv, Wo, bias)
    constexpr size_t kCvtElems = (size_t)kS * kD + 2 * (size_t)kD * kD
                               + 2 * (size_t)kGHD * kD + kNQKV;
    cvt_all<<<(kCvtElems + 1023) / 1024, 256, 0, stream>>>(
        x, Wq, Wk, Wv, Wo, bq, bk, bv, xf, wqkvf, wof, bqkv);

    // fused QKV projection (16-wave, 4-way K-phase split)
    gemm_qkv<<<(kNQKV / 128) * (kS / 128), 1024, 0, stream>>>(
        xf, wqkvf, bqkv, qb16, kb16, vt16, kD, kNQKV / 128);

    // MFMA flash attention (frozen R11 structure)
    gqa_attn_mfma<<<dim3(kS / 32, kG), 512, 0, stream>>>(qb16, kb16, vt16, aoh);

    // output projection (16-wave, 4-way K-phase split)
    gemm_o<<<(kD / 128) * (kS / 128), 1024, 0, stream>>>(
        aoh, wof, bo, out, kD, kD, kD / 128);
}

// Round 14
// 132.248 us; speedup vs baseline: 1.1294x; 1.1294x over previous
//
#include <hip/hip_runtime.h>
#include <hip/hip_bf16.h>

// Problem constants (B=1)
constexpr int kS   = 2048;
constexpr int kD   = 2048;
constexpr int kG   = 8;
constexpr int kHD  = 64;
constexpr int kGHD = 512;
constexpr int kNQKV = kD + 2 * kGHD;   // 3072 fused QKV output cols

// 0.125 (1/sqrt(HD)) * log2(e): folds softmax scale AND exp->exp2 into Wq/bq
constexpr float kQScale = 0.125f * 1.4426950408889634f;

typedef __attribute__((ext_vector_type(8)))  _Float16 f16x8;
typedef __attribute__((ext_vector_type(4)))  float    f32x4;
typedef __attribute__((ext_vector_type(16))) float    f32x16;
typedef __attribute__((ext_vector_type(4)))  unsigned int u32x4;

__device__ __forceinline__ ushort f2h(float x) {
    return __builtin_bit_cast(ushort, (_Float16)x);
}
__device__ __forceinline__ float fast_exp2(float x) {
    return __builtin_amdgcn_exp2f(x);   // v_exp_f32 is base-2
}
__device__ __forceinline__ unsigned int pkrtz(float a, float b) {
    auto r = __builtin_amdgcn_cvt_pkrtz(a, b);   // lo = a, hi = b
    return __builtin_bit_cast(unsigned int, r);
}

// ---------------------------------------------------------------------------
// ONE fused conversion kernel: x,Wq,Wk,Wv,Wo -> f16 (+scale on Wq), bias vec.
// ---------------------------------------------------------------------------
__global__ __launch_bounds__(256) void cvt_all(
    const float* __restrict__ x,  const float* __restrict__ Wq,
    const float* __restrict__ Wk, const float* __restrict__ Wv,
    const float* __restrict__ Wo, const float* __restrict__ bq,
    const float* __restrict__ bk, const float* __restrict__ bv,
    ushort* __restrict__ xf, ushort* __restrict__ wqkvf,
    ushort* __restrict__ wof, float* __restrict__ bqkv)
{
    constexpr size_t Nx  = (size_t)kS * kD;
    constexpr size_t NWq = (size_t)kD * kD;
    constexpr size_t NWk = (size_t)kGHD * kD;
    constexpr size_t e1 = Nx, e2 = e1 + NWq, e3 = e2 + NWk, e4 = e3 + NWk,
                     e5 = e4 + NWq;
    const size_t i = ((size_t)blockIdx.x * 256 + threadIdx.x) * 4;

    const float* src; ushort* dst; float scale = 1.f;
    if (i < e1)      { src = x  + i;        dst = xf + i; }
    else if (i < e2) { src = Wq + (i - e1); dst = wqkvf + (i - e1); scale = kQScale; }
    else if (i < e3) { src = Wk + (i - e2); dst = wqkvf + NWq + (i - e2); }
    else if (i < e4) { src = Wv + (i - e3); dst = wqkvf + NWq + NWk + (i - e3); }
    else if (i < e5) { src = Wo + (i - e4); dst = wof + (i - e4); }
    else {
        const size_t j = i - e5;   // bias segment [0, 3072)
        #pragma unroll
        for (int u = 0; u < 4; ++u) {
            const size_t jj = j + u;
            if (jj < kD)              bqkv[jj] = bq[jj] * kQScale;
            else if (jj < kD + kGHD)  bqkv[jj] = bk[jj - kD];
            else if (jj < (size_t)kNQKV) bqkv[jj] = bv[jj - kD - kGHD];
        }
        return;
    }
    const float4 v = *(const float4*)src;
    ushort4 o;
    o.x = f2h(v.x * scale); o.y = f2h(v.y * scale);
    o.z = f2h(v.z * scale); o.w = f2h(v.w * scale);
    *(ushort4*)dst = o;
}

// ---------------------------------------------------------------------------
// 8-wave 128x128 f16 GEMM, 2-way K-PHASE SPLIT (R12 structure, validated)
// + R14: near-square per-XCD chunk mapping.  blockIdx.x & 7 = XCD; each XCD
// owns a CMxCN chunk of the tile grid -> fetch (CM+CN) panels instead of
// (rows+allcols).  qkv: 8x6 chunks (13->7 MB/XCD); o: 4x8 (9->6 MB/XCD).
// ---------------------------------------------------------------------------
#define GEMM_PRELUDE(Aptr, Bptr, CM, CN, NCHX)                                \
    const int xcd  = blockIdx.x & 7;                                          \
    const int idx  = blockIdx.x >> 3;                                         \
    const int m0   = ((xcd / (NCHX)) * (CM) + idx % (CM)) * 128;              \
    const int n0   = ((xcd % (NCHX)) * (CN) + idx / (CM)) * 128;              \
    const int tid  = threadIdx.x;                                             \
    const int w    = tid >> 6;                                                \
    const int lane = tid & 63;                                                \
    const int kph  = w >> 2;                                                  \
    const int wm   = (w & 3) >> 1;                                            \
    const int wn   = w & 1;                                                   \
    const int fr   = lane & 15;                                               \
    const int kq   = lane >> 4;                                               \
    const int srow = w * 16 + (lane >> 3);                                    \
    const int sslot = ((lane & 7) ^ (lane >> 3)) * 8;                         \
    const ushort* gA = (Aptr) + (size_t)(m0 + srow) * K + sslot;              \
    const ushort* gB = (Bptr) + (size_t)(n0 + srow) * K + sslot;              \
    f32x4 acc[4][4];                                                          \
    _Pragma("unroll")                                                         \
    for (int mi = 0; mi < 4; ++mi)                                            \
        _Pragma("unroll")                                                     \
        for (int ni = 0; ni < 4; ++ni) {                                      \
            f32x4 z = {0.f, 0.f, 0.f, 0.f};                                   \
            acc[mi][ni] = z;                                                  \
        }

#define GEMM_STAGE(buf, k0)                                                   \
    do {                                                                      \
        _Pragma("unroll")                                                     \
        for (int j = 0; j < 2; ++j) {                                         \
            __builtin_amdgcn_global_load_lds(                                 \
                (const __attribute__((address_space(1))) void*)               \
                    (gA + (size_t)j * 8 * K + (k0)),                          \
                (__attribute__((address_space(3))) void*)                    \
                    &lds[buf][0][(w * 16 + j * 8) * 64],                      \
                16, 0, 0);                                                    \
            __builtin_amdgcn_global_load_lds(                                 \
                (const __attribute__((address_space(1))) void*)               \
                    (gB + (size_t)j * 8 * K + (k0)),                          \
                (__attribute__((address_space(3))) void*)                    \
                    &lds[buf][1][(w * 16 + j * 8) * 64],                      \
                16, 0, 0);                                                    \
        }                                                                     \
    } while (0)

#define GEMM_KLOOP                                                            \
    GEMM_STAGE(0, 0);                                                         \
    __syncthreads();                                                          \
    int cur = 0;                                                              \
    for (int k0 = 0; k0 < K; k0 += 64) {                                      \
        if (k0 + 64 < K) GEMM_STAGE(cur ^ 1, k0 + 64);                        \
        f16x8 af[4], bf[4];                                                   \
        _Pragma("unroll")                                                     \
        for (int f = 0; f < 4; ++f) {                                         \
            const int ra = wm * 64 + f * 16 + fr;                             \
            const int rb = wn * 64 + f * 16 + fr;                             \
            af[f] = *(const f16x8*)&lds[cur][0][ra * 64                       \
                        + (((kph * 4 + kq) ^ (ra & 7)) * 8)];                 \
            bf[f] = *(const f16x8*)&lds[cur][1][rb * 64                       \
                        + (((kph * 4 + kq) ^ (rb & 7)) * 8)];                 \
        }                                                                     \
        __builtin_amdgcn_s_setprio(1);                                        \
        _Pragma("unroll")                                                     \
        for (int mi = 0; mi < 4; ++mi)                                        \
            _Pragma("unroll")                                                 \
            for (int ni = 0; ni < 4; ++ni)                                    \
                acc[mi][ni] = __builtin_amdgcn_mfma_f32_16x16x32_f16(         \
                    af[mi], bf[ni], acc[mi][ni], 0, 0, 0);                    \
        __builtin_amdgcn_s_setprio(0);                                        \
        __syncthreads();                                                      \
        cur ^= 1;                                                             \
    }

// merge K-phase partials through the (dead) staging LDS; leaves final acc
// in waves 0-3.  [chunk][lane][4] layout -> conflict-free b128.
#define GEMM_MERGE                                                            \
    float* mlds = (float*)&lds[0][0][0];                                      \
    if (w >= 4) {                                                             \
        _Pragma("unroll")                                                     \
        for (int c = 0; c < 16; ++c)                                          \
            *(f32x4*)&mlds[(w - 4) * 4096 + c * 256 + lane * 4]               \
                = acc[c >> 2][c & 3];                                         \
    }                                                                         \
    __syncthreads();                                                          \
    if (w < 4) {                                                              \
        _Pragma("unroll")                                                     \
        for (int c = 0; c < 16; ++c) {                                        \
            const f32x4 part = *(const f32x4*)&mlds[w * 4096 + c * 256        \
                                                    + lane * 4];              \
            acc[c >> 2][c & 3] += part;                                       \
        }                                                                     \
    }

// ---------------------------------------------------------------------------
// QKV GEMM: C = A @ B^T + bias -> f16; q [S][D], k [S][GHD], v^T [GHD][S]
// grid 384 = 8 XCD-chunks of 8m x 6n.
// ---------------------------------------------------------------------------
__global__ __launch_bounds__(512, 4) void gemm_qkv(
    const ushort* __restrict__ Af, const ushort* __restrict__ Bf,
    const float* __restrict__ bias,
    ushort* __restrict__ qb16, ushort* __restrict__ kb16, ushort* __restrict__ vt16,
    int K)
{
    __shared__ ushort lds[2][2][128 * 64];   // [buf][A/B], 64 KB

    GEMM_PRELUDE(Af, Bf, 8, 6, 4)
    GEMM_KLOOP
    GEMM_MERGE

    if (w < 4) {
        const int seg = (n0 < kD) ? 0 : (n0 < kD + kGHD) ? 1 : 2;
        #pragma unroll
        for (int ni = 0; ni < 4; ++ni) {
            const int ncol = n0 + wn * 64 + ni * 16 + fr;
            const float bv = bias[ncol];
            #pragma unroll
            for (int mi = 0; mi < 4; ++mi) {
                #pragma unroll
                for (int i = 0; i < 4; ++i) {
                    const int row = m0 + wm * 64 + mi * 16 + kq * 4 + i;
                    const ushort u = f2h(acc[mi][ni][i] + bv);
                    if (seg == 0)      qb16[(size_t)row * kD   + ncol]              = u;
                    else if (seg == 1) kb16[(size_t)row * kGHD + (ncol - kD)]       = u;
                    else               vt16[(size_t)(ncol - kD - kGHD) * kS + row]  = u;
                }
            }
        }
    }
}

// ---------------------------------------------------------------------------
// O-proj GEMM: out(fp32) = A @ W^T + bias  (single-f16 A)
// grid 256 = 8 XCD-chunks of 4m x 8n.
// ---------------------------------------------------------------------------
__global__ __launch_bounds__(512, 4) void gemm_o(
    const ushort* __restrict__ Af, const ushort* __restrict__ Bf,
    const float* __restrict__ bias, float* __restrict__ C, int K, int N)
{
    __shared__ ushort lds[2][2][128 * 64];

    GEMM_PRELUDE(Af, Bf, 4, 8, 2)
    GEMM_KLOOP
    GEMM_MERGE

    if (w < 4) {
        #pragma unroll
        for (int ni = 0; ni < 4; ++ni) {
            const int ncol = n0 + wn * 64 + ni * 16 + fr;
            const float bv = bias[ncol];
            #pragma unroll
            for (int mi = 0; mi < 4; ++mi)
                #pragma unroll
                for (int i = 0; i < 4; ++i) {
                    const int row = m0 + wm * 64 + mi * 16 + kq * 4 + i;
                    C[(size_t)row * N + ncol] = acc[mi][ni][i] + bv;
                }
        }
    }
}

// ---------------------------------------------------------------------------
// MFMA flash attention (FROZEN from R11: 32x32x16 f16, in-register P via
// cvt_pkrtz + permlane32_swap, in-block kv-split, flash-decode merge).
// ---------------------------------------------------------------------------
__global__ __launch_bounds__(512, 4) void gqa_attn_mfma(
    const ushort* __restrict__ qb,   // [S][D] f16 (prescaled by kQScale)
    const ushort* __restrict__ kb,   // [S][GHD] f16
    const ushort* __restrict__ vt,   // [GHD][S] f16 (V transposed)
    ushort* __restrict__ oh)
{
    __shared__ ushort Kt[2][2][64 * 64];   // [half][dbuf] swizzled K (32 KB)
    __shared__ ushort Vt[2][2][64 * 64];   // [half][dbuf] swizzled V^T (32 KB)

    const int g    = blockIdx.y;
    const int q0   = blockIdx.x * 32;
    const int tid  = threadIdx.x;
    const int w    = tid >> 6;
    const int lane = tid & 63;
    const int hw   = w & 3;             // head-in-group
    const int half = w >> 2;            // kv half
    const int ql   = lane & 31;         // q-col for this lane
    const int hi   = lane >> 5;
    const int h    = g * 4 + hw;
    const int tbase = half * (kS / 2);

    const int r0 = hw * 16 + (lane >> 3);
    const int ss = (lane & 7) ^ (r0 & 7);   // pre-swizzled source slot

#define ATTN_STAGE(buf, t)                                                         \
    do {                                                                           \
        __builtin_amdgcn_global_load_lds(                                          \
            (const __attribute__((address_space(1))) void*)                       \
                (kb + (size_t)(tbase + (t) + r0) * kGHD + g * kHD + ss * 8),       \
            (__attribute__((address_space(3))) void*)(&Kt[half][buf][(hw * 16) * 64]), \
            16, 0, 0);                                                             \
        __builtin_amdgcn_global_load_lds(                                          \
            (const __attribute__((address_space(1))) void*)                       \
                (kb + (size_t)(tbase + (t) + r0 + 8) * kGHD + g * kHD + ss * 8),   \
            (__attribute__((address_space(3))) void*)(&Kt[half][buf][(hw * 16 + 8) * 64]), \
            16, 0, 0);                                                             \
        __builtin_amdgcn_global_load_lds(                                          \
            (const __attribute__((address_space(1))) void*)                       \
                (vt + (size_t)(g * kHD + r0) * kS + tbase + (t) + ss * 8),         \
            (__attribute__((address_space(3))) void*)(&Vt[half][buf][(hw * 16) * 64]), \
            16, 0, 0);                                                             \
        __builtin_amdgcn_global_load_lds(                                          \
            (const __attribute__((address_space(1))) void*)                       \
                (vt + (size_t)(g * kHD + r0 + 8) * kS + tbase + (t) + ss * 8),     \
            (__attribute__((address_space(3))) void*)(&Vt[half][buf][(hw * 16 + 8) * 64]), \
            16, 0, 0);                                                             \
    } while (0)

    ATTN_STAGE(0, 0);

    // hoist Q fragments (B-operand: lane&31 = q-col, hi = d-half-of-16)
    f16x8 qf[4];
    #pragma unroll
    for (int ks = 0; ks < 4; ++ks)
        qf[ks] = *(const f16x8*)&qb[(size_t)(q0 + ql) * kD + h * kHD + ks * 16 + hi * 8];

    float mrow = -1e30f, lrow = 0.f;    // stats for q = q0 + ql (lane-local)
    f32x16 oacc[2];
    #pragma unroll
    for (int db = 0; db < 2; ++db)
        #pragma unroll
        for (int r = 0; r < 16; ++r) oacc[db][r] = 0.f;

    int cur = 0;
    for (int t = 0; t < kS / 2; t += 64) {
        __syncthreads();   // buf[cur] staged (vmcnt drained); buf[cur^1] reads done

        if (t + 64 < kS / 2) ATTN_STAGE(cur ^ 1, t + 64);

        // --- QK^T (swapped): all 8 K-frag reads, then one MFMA cluster ---
        f32x16 sc[2];
        #pragma unroll
        for (int kb2 = 0; kb2 < 2; ++kb2)
            #pragma unroll
            for (int r = 0; r < 16; ++r) sc[kb2][r] = 0.f;

        {
            f16x8 kf[2][4];
            #pragma unroll
            for (int kb2 = 0; kb2 < 2; ++kb2)
                #pragma unroll
                for (int ks = 0; ks < 4; ++ks)
                    kf[kb2][ks] = *(const f16x8*)&Kt[half][cur][(kb2 * 32 + ql) * 64
                                       + (((2 * ks + hi) ^ (ql & 7)) * 8)];
            __builtin_amdgcn_s_setprio(1);
            #pragma unroll
            for (int ks = 0; ks < 4; ++ks) {
                sc[0] = __builtin_amdgcn_mfma_f32_32x32x16_f16(kf[0][ks], qf[ks], sc[0], 0, 0, 0);
                sc[1] = __builtin_amdgcn_mfma_f32_32x32x16_f16(kf[1][ks], qf[ks], sc[1], 0, 0, 0);
            }
            __builtin_amdgcn_s_setprio(0);
        }

        // --- in-lane softmax: 32 values per lane, 1 shfl per reduce ---
        float mt = sc[0][0];
        #pragma unroll
        for (int kb2 = 0; kb2 < 2; ++kb2)
            #pragma unroll
            for (int r = 0; r < 16; ++r) mt = fmaxf(mt, sc[kb2][r]);
        mt = fmaxf(mt, __shfl_xor(mt, 32));

        if (__any(mt > mrow + 11.5f)) {      // defer-max (T13), log2 domain
            const float mnew = (mt > mrow + 11.5f) ? mt : mrow;
            const float c = fast_exp2(mrow - mnew);
            lrow *= c;
            mrow = mnew;
            #pragma unroll
            for (int db = 0; db < 2; ++db)
                #pragma unroll
                for (int r = 0; r < 16; ++r) oacc[db][r] *= c;
        }

        float ps = 0.f;
        #pragma unroll
        for (int kb2 = 0; kb2 < 2; ++kb2)
            #pragma unroll
            for (int r = 0; r < 16; ++r) {
                const float p = fast_exp2(sc[kb2][r] - mrow);
                sc[kb2][r] = p;
                ps += p;
            }
        ps += __shfl_xor(ps, 32);
        lrow += ps;

        // --- PV: build P-frags, all 8 V-frag reads, one MFMA cluster ---
        {
            f16x8 pf[2][2];
            #pragma unroll
            for (int kb2 = 0; kb2 < 2; ++kb2)
                #pragma unroll
                for (int ks = 0; ks < 2; ++ks) {
                    unsigned int a0 = pkrtz(sc[kb2][8 * ks + 0], sc[kb2][8 * ks + 1]);
                    unsigned int a1 = pkrtz(sc[kb2][8 * ks + 2], sc[kb2][8 * ks + 3]);
                    unsigned int b0 = pkrtz(sc[kb2][8 * ks + 4], sc[kb2][8 * ks + 5]);
                    unsigned int b1 = pkrtz(sc[kb2][8 * ks + 6], sc[kb2][8 * ks + 7]);
                    asm volatile("v_permlane32_swap_b32 %0, %1" : "+v"(a0), "+v"(b0));
                    asm volatile("v_permlane32_swap_b32 %0, %1" : "+v"(a1), "+v"(b1));
                    const u32x4 pu = {a0, a1, b0, b1};
                    pf[kb2][ks] = __builtin_bit_cast(f16x8, pu);
                }
            f16x8 vf[2][2][2];
            #pragma unroll
            for (int kb2 = 0; kb2 < 2; ++kb2)
                #pragma unroll
                for (int ks = 0; ks < 2; ++ks)
                    #pragma unroll
                    for (int db = 0; db < 2; ++db)
                        vf[kb2][ks][db] = *(const f16x8*)&Vt[half][cur][(db * 32 + ql) * 64
                                             + (((4 * kb2 + 2 * ks + hi) ^ (ql & 7)) * 8)];
            __builtin_amdgcn_s_setprio(1);
            #pragma unroll
            for (int kb2 = 0; kb2 < 2; ++kb2)
                #pragma unroll
                for (int ks = 0; ks < 2; ++ks)
                    #pragma unroll
                    for (int db = 0; db < 2; ++db)
                        oacc[db] = __builtin_amdgcn_mfma_f32_32x32x16_f16(
                            vf[kb2][ks][db], pf[kb2][ks], oacc[db], 0, 0, 0);
            __builtin_amdgcn_s_setprio(0);
        }
        cur ^= 1;
    }
#undef ATTN_STAGE

    // --- flash-decode merge of the two kv-halves via (dead) staging LDS ---
    __syncthreads();   // all waves done with K/V tiles
    float* ox  = (float*)(&Kt[0][0][0]);   // [32 regs][256 (head,lane)] = 32 KB
    float* mlx = (float*)(&Vt[0][0][0]);   // [2][256]
    const int idx = hw * 64 + lane;

    if (half == 1) {
        #pragma unroll
        for (int db = 0; db < 2; ++db)
            #pragma unroll
            for (int r = 0; r < 16; ++r)
                ox[(db * 16 + r) * 256 + idx] = oacc[db][r];
        mlx[idx]       = mrow;
        mlx[256 + idx] = lrow;
    }
    __syncthreads();

    if (half == 0) {
        const float m2 = mlx[idx];
        const float l2 = mlx[256 + idx];
        const float mm = fmaxf(mrow, m2);
        const float c1 = fast_exp2(mrow - mm);
        const float c2 = fast_exp2(m2 - mm);
        const float inv = 1.f / (lrow * c1 + l2 * c2);
        const size_t rowbase = (size_t)(q0 + ql) * kD + hw * kGHD + g * kHD;
        #pragma unroll
        for (int db = 0; db < 2; ++db) {
            #pragma unroll
            for (int rr = 0; rr < 4; ++rr) {
                ushort4 o4;
                o4.x = f2h((oacc[db][rr * 4 + 0] * c1 + ox[(db * 16 + rr * 4 + 0) * 256 + idx] * c2) * inv);
                o4.y = f2h((oacc[db][rr * 4 + 1] * c1 + ox[(db * 16 + rr * 4 + 1) * 256 + idx] * c2) * inv);
                o4.z = f2h((oacc[db][rr * 4 + 2] * c1 + ox[(db * 16 + rr * 4 + 2) * 256 + idx] * c2) * inv);
                o4.w = f2h((oacc[db][rr * 4 + 3] * c1 + ox[(db * 16 + rr * 4 + 3) * 256 + idx] * c2) * inv);
                *(ushort4*)&oh[rowbase + db * 32 + rr * 8 + hi * 4] = o4;
            }
        }
    }
}

// ---------------------------------------------------------------------------
extern "C" void kernel_launch(void* const* d_in, const int* in_sizes, int n_in,
                              void* d_out, int out_size, void* d_ws, size_t ws_size,
                              hipStream_t stream)
{
    const float* x  = (const float*)d_in[0];
    const float* Wq = (const float*)d_in[1];
    const float* bq = (const float*)d_in[2];
    const float* Wk = (const float*)d_in[3];
    const float* bk = (const float*)d_in[4];
    const float* Wv = (const float*)d_in[5];
    const float* bv = (const float*)d_in[6];
    const float* Wo = (const float*)d_in[7];
    const float* bo = (const float*)d_in[8];
    float* out = (float*)d_out;

    // workspace layout (~48 MB)
    char* p = (char*)d_ws;
    ushort* xf    = (ushort*)p; p += (size_t)kS * kD * 2;        // x f16
    ushort* wqkvf = (ushort*)p; p += (size_t)kNQKV * kD * 2;     // Wqkv f16 (Wq pre-scaled)
    ushort* wof   = (ushort*)p; p += (size_t)kD * kD * 2;        // Wo f16
    float*  bqkv  = (float*)p;  p += 16384;
    ushort* qb16  = (ushort*)p; p += (size_t)kS * kD * 2;
    ushort* kb16  = (ushort*)p; p += (size_t)kS * kGHD * 2;
    ushort* vt16  = (ushort*)p; p += (size_t)kGHD * kS * 2;
    ushort* aoh   = (ushort*)p;                                  // attn out f16

    // single fused conversion pass (x, Wq*s, Wk, Wv, Wo, bias)
    constexpr size_t kCvtElems = (size_t)kS * kD + 2 * (size_t)kD * kD
                               + 2 * (size_t)kGHD * kD + kNQKV;
    cvt_all<<<(kCvtElems + 1023) / 1024, 256, 0, stream>>>(
        x, Wq, Wk, Wv, Wo, bq, bk, bv, xf, wqkvf, wof, bqkv);

    // fused QKV projection (R12 structure + 8x6 XCD chunks)
    gemm_qkv<<<(kNQKV / 128) * (kS / 128), 512, 0, stream>>>(
        xf, wqkvf, bqkv, qb16, kb16, vt16, kD);

    // MFMA flash attention (frozen R11 structure)
    gqa_attn_mfma<<<dim3(kS / 32, kG), 512, 0, stream>>>(qb16, kb16, vt16, aoh);

    // output projection (R12 structure + 4x8 XCD chunks)
    gemm_o<<<(kD / 128) * (kS / 128), 512, 0, stream>>>(
        aoh, wof, bo, out, kD, kD);
}